// Round 1
// baseline (107.338 us; speedup 1.0000x reference)
//
#include <hip/hip_runtime.h>
#include <math.h>

#define KOBJ 256
#define B1   256              // partial-accumulator blocks
#define NW   4                // waves per block
#define WSTR 257              // per-wave bucket stride (bank-conflict pad)
#define CHUNK 200             // heavy: points per block (500*200 = 100000 exactly)
#define QMIN 0.5f
#define BETA_CLIP_C (1.0f - 1e-5f)

typedef unsigned long long u64;

// ---------------- Kernel A: per-block LDS accumulation with PER-WAVE buckets
// (removes same-address inter-wave atomic serialization), k-major partial writes.
__global__ __launch_bounds__(256) void partials(
    const float*  __restrict__ pred_beta,
    const float*  __restrict__ pred_energy,
    const float2* __restrict__ pred_pos,
    const float*  __restrict__ pred_time,
    const float2* __restrict__ pred_id2,
    const float*  __restrict__ t_energy,
    const float2* __restrict__ t_pos,
    const float*  __restrict__ t_time,
    const int*    __restrict__ t_idx,
    u64*    __restrict__ pk_part,   // [K][B1]
    float*  __restrict__ cnt_part,  // [K][B1]
    float*  __restrict__ den_part,  // [K][B1]
    float*  __restrict__ num_part,  // [K][B1]
    float*  __restrict__ noise_part,// [B1]
    unsigned* __restrict__ tick,    // zeroed here each iteration (used by finalk)
    int n)
{
    __shared__ u64   spk[NW][WSTR];                   // 8.2 KB
    __shared__ float scnt[NW][WSTR], sden[NW][WSTR], snum[NW][WSTR]; // 12.3 KB
    __shared__ float snoise[256];
    int t = threadIdx.x;
    int b = blockIdx.x;
    int w = t >> 6;
    if (b == 0 && t == 0) *tick = 0u;   // reset ticket for finalk (cross-kernel visible)
    for (int i = t; i < NW * WSTR; i += 256) {
        ((u64*)spk)[i] = 0;
        ((float*)scnt)[i] = 0.f;
        ((float*)sden)[i] = 0.f;
        ((float*)snum)[i] = 0.f;
    }
    __syncthreads();

    float noise = 0.0f;
    for (int i = b * 256 + t; i < n; i += B1 * 256) {
        int tid = t_idx[i];
        float braw = pred_beta[i];
        float beta = fminf(fmaxf(braw, 0.0f), BETA_CLIP_C);
        if (tid >= 0) {
            atomicAdd(&scnt[w][tid], 1.0f);
            u64 key = ((u64)__float_as_uint(beta) << 32) |
                      (u64)(0x7FFFFFFFu - (unsigned)i);   // max beta, tie -> lowest index
            atomicMax(&spk[w][tid], key);
            float te = t_energy[i];
            float ew = (te > 10.0f) ? 1.0f : fmaxf(0.0f, (te - 0.5f) / 9.5f);
            float de = te - pred_energy[i];
            float el = de * de / (te + 1.0f);
            float2 tp = t_pos[i];
            float2 pp = pred_pos[i];
            float dpx = tp.x - pp.x, dpy = tp.y - pp.y;
            float pl = (dpx * dpx + dpy * dpy) * 0.01f;
            float dt = t_time[i] - pred_time[i];
            float tl = dt * dt;
            float2 id0 = pred_id2[3 * i];
            float2 id1 = pred_id2[3 * i + 1];
            float2 id2 = pred_id2[3 * i + 2];
            float cs = id0.x * id0.x + id0.y * id0.y + id1.x * id1.x +
                       id1.y * id1.y + id2.x * id2.x + id2.y * id2.y;
            cs *= (1e-8f / 6.0f);
            float mask = (braw < 0.1f) ? 0.0f : 1.0f;  // PAYLOAD_BETA_CLIP on raw beta
            float wgt = mask * ew * beta;
            atomicAdd(&sden[w][tid], beta);
            atomicAdd(&snum[w][tid], (el + pl + tl + cs) * wgt);
        } else {
            noise += beta;
        }
    }
    __syncthreads();
    // fold 4 wave-buckets -> 1 (stride-1 reads, conflict-free)
    u64 pk = spk[0][t];
    { u64 q = spk[1][t]; if (q > pk) pk = q; }
    { u64 q = spk[2][t]; if (q > pk) pk = q; }
    { u64 q = spk[3][t]; if (q > pk) pk = q; }
    float cnt = scnt[0][t] + scnt[1][t] + scnt[2][t] + scnt[3][t];
    float den = sden[0][t] + sden[1][t] + sden[2][t] + sden[3][t];
    float num = snum[0][t] + snum[1][t] + snum[2][t] + snum[3][t];
    int o = t * B1 + b;
    pk_part[o]  = pk;
    cnt_part[o] = cnt;
    den_part[o] = den;
    num_part[o] = num;
    snoise[t] = noise;
    __syncthreads();
    for (int s = 128; s > 0; s >>= 1) {
        if (t < s) snoise[t] += snoise[t + s];
        __syncthreads();
    }
    if (t == 0) noise_part[b] = snoise[0];
}

// ---------------- Kernel B: one block per object; coalesced row reduce
__global__ __launch_bounds__(256) void merge(
    const float2* __restrict__ pred_ccoords,
    const u64*    __restrict__ pk_part,
    const float*  __restrict__ cnt_part,
    const float*  __restrict__ den_part,
    const float*  __restrict__ num_part,
    float4* __restrict__ objA,   // (xk, yk, qa, cnt)
    float4* __restrict__ objB)   // (pay, lb, valid, 0)
{
    __shared__ u64   spk[256];
    __shared__ float scnt[256], sden[256], snum[256];
    int k = blockIdx.x;
    int b = threadIdx.x;
    int o = k * B1 + b;
    u64 pk = pk_part[o];
    float cnt = cnt_part[o];
    float den = den_part[o];
    float nsum = num_part[o];
    spk[b] = pk; scnt[b] = cnt; sden[b] = den; snum[b] = nsum;
    __syncthreads();
    for (int s = 128; s > 0; s >>= 1) {
        if (b < s) {
            u64 p = spk[b + s]; if (p > spk[b]) spk[b] = p;
            scnt[b] += scnt[b + s];
            sden[b] += sden[b + s];
            snum[b] += snum[b + s];
        }
        __syncthreads();
    }
    if (b == 0) {
        float cs = scnt[0];
        bool valid = cs > 0.f;
        float xk = 0.f, yk = 0.f, qa = 0.f, lb = 0.f, pay = 0.f;
        if (valid) {
            u64 p = spk[0];
            unsigned a = 0x7FFFFFFFu - (unsigned)(p & 0xFFFFFFFFull);
            float ba = __uint_as_float((unsigned)(p >> 32));
            float2 cc = pred_ccoords[a];
            xk = cc.x; yk = cc.y;
            float at = atanhf(ba);
            qa = at * at + QMIN;
            lb = 1.0f - ba;
            pay = snum[0] / fmaxf(sden[0], 1e-6f);
        }
        objA[k] = make_float4(xk, yk, qa, cs);
        objB[k] = make_float4(pay, lb, valid ? 1.f : 0.f, 0.f);
    }
}

// ---------------- Kernel C: N x K repulsion only in the hot loop (8 VALU ops/pair);
// attraction + own-pair exclusion handled as an O(CHUNK) per-block LDS correction.
// CHUNK=200 -> 500 blocks -> ~2.0 balanced blocks/CU (worst-CU 400 inner iters vs 512).
__global__ __launch_bounds__(256) void heavy(
    const float*  __restrict__ pred_beta,
    const float2* __restrict__ pred_ccoords,
    const int*    __restrict__ t_idx,
    const float4* __restrict__ objA,
    float* __restrict__ rep_part,   // [K][hstr]
    float* __restrict__ att_part,   // [K][hstr]
    int n, int hstr)
{
    __shared__ float4 pts[CHUNK];
    __shared__ float corrR[KOBJ], corrA[KOBJ];
    int t = threadIdx.x;
    corrR[t] = 0.f;
    corrA[t] = 0.f;
    float4 pt = make_float4(0.f, 0.f, 0.f, __int_as_float(-2));  // q=0 => inert
    int p = blockIdx.x * CHUNK + t;
    if (t < CHUNK) {
        if (p < n) {
            float beta = fminf(fmaxf(pred_beta[p], 0.0f), BETA_CLIP_C);
            float at = atanhf(beta);
            float2 cc = pred_ccoords[p];
            pt = make_float4(cc.x, cc.y, at * at + QMIN, __int_as_float(t_idx[p]));
        }
        pts[t] = pt;
    }
    float4 oa = objA[t];
    float xk = oa.x, yk = oa.y;
    __syncthreads();

    // own-pair correction: thread t handles its own point (register pt).
    // att_k = sum_{i in k} d2(i, x_k) * q_i   (this IS the attraction term)
    // corrR removes the own-pair h*q that the unconditional loop below adds.
    int tid = __float_as_int(pt.w);
    if (t < CHUNK && tid >= 0) {
        float4 ok = objA[tid];                         // 4 KB table, L1/L2-hot
        float dx = pt.x - ok.x, dy = pt.y - ok.y;
        float d2 = fmaf(dy, dy, fmaf(dx, dx, 1e-6f));  // eps folded (matches prior accepted numerics)
        float r = __builtin_amdgcn_sqrtf(d2);
        float h = fmaxf(0.0f, 1.0f - r);
        atomicAdd(&corrA[tid], d2 * pt.z);
        atomicAdd(&corrR[tid], h * pt.z);
    }

    float rep = 0.f;
    #pragma unroll 8
    for (int j = 0; j < CHUNK; ++j) {
        float4 s = pts[j];                    // wave-uniform address -> bank broadcast
        float dx = s.x - xk, dy = s.y - yk;
        float d2 = fmaf(dy, dy, fmaf(dx, dx, 1e-6f));
        float r = __builtin_amdgcn_sqrtf(d2);
        float h = fmaxf(0.0f, 1.0f - r);
        rep = fmaf(h, s.z, rep);              // unconditional; own pair removed via corrR
    }
    __syncthreads();
    int o = t * hstr + blockIdx.x;
    rep_part[o] = rep - corrR[t];
    att_part[o] = corrA[t];
}

// ---------------- Kernel D: per-object reduce of heavy partials + fused scalar finish.
// Block k publishes its object scalar via device-scope atomicExch (coherent across
// XCD L2s); last block (ticket) re-reads via atomicAdd(p, 0.0f) and does the same
// deterministic float4 tree-reduce the old final2 did.
__global__ __launch_bounds__(256) void finalk(
    const float4* __restrict__ objA,
    const float4* __restrict__ objB,
    const float*  __restrict__ rep_part,
    const float*  __restrict__ att_part,
    const float*  __restrict__ noise_part,
    float*    __restrict__ objCf,   // [KOBJ*4] atomic slots (s0, valid, cnt, -)
    unsigned* __restrict__ tick,
    float*    __restrict__ out,
    int n, int nbh, int hstr)
{
    __shared__ float srep[256], satt[256];
    __shared__ float4 sred[256];
    __shared__ int lastflag;
    int k = blockIdx.x;
    int b = threadIdx.x;
    float rep = 0.f, att = 0.f;
    for (int j = b; j < nbh; j += 256) {
        rep += rep_part[k * hstr + j];
        att += att_part[k * hstr + j];
    }
    srep[b] = rep; satt[b] = att;
    __syncthreads();
    for (int s = 128; s > 0; s >>= 1) {
        if (b < s) { srep[b] += srep[b + s]; satt[b] += satt[b + s]; }
        __syncthreads();
    }
    if (b == 0) {
        float4 a  = objA[k];
        float4 b4 = objB[k];
        float cnt = a.w, qa = a.z, valid = b4.z;
        float vatt = valid * satt[0] * qa / fmaxf(cnt, 1.0f);
        float vrep = valid * srep[0] * qa / fmaxf((float)n - cnt, 1.0f);
        float s0 = vatt + vrep + b4.y + b4.x;
        atomicExch(&objCf[4 * k + 0], s0);     // device-scope -> coherence point
        atomicExch(&objCf[4 * k + 1], valid);
        atomicExch(&objCf[4 * k + 2], cnt);
        __threadfence();                        // release before ticket
        unsigned prev = atomicAdd(tick, 1u);
        lastflag = (prev == (unsigned)(KOBJ - 1)) ? 1 : 0;
    }
    __syncthreads();                            // broadcast lastflag (block-uniform)
    if (lastflag) {
        __threadfence();                        // acquire side
        float s0  = atomicAdd(&objCf[4 * b + 0], 0.0f);  // coherent atomic read
        float val = atomicAdd(&objCf[4 * b + 1], 0.0f);
        float cnt = atomicAdd(&objCf[4 * b + 2], 0.0f);
        float noi = noise_part[b];              // cross-kernel data: plain load OK
        sred[b] = make_float4(s0, val, cnt, noi);
        __syncthreads();
        for (int s = 128; s > 0; s >>= 1) {
            if (b < s) {
                float4 x = sred[b], y = sred[b + s];
                sred[b] = make_float4(x.x + y.x, x.y + y.y, x.z + y.z, x.w + y.w);
            }
            __syncthreads();
        }
        if (b == 0) {
            float4 r = sred[0];
            float nv = fmaxf(r.y, 1.0f);                    // n_valid
            float nnoise = fmaxf((float)n - r.z, 1.0f);     // noise count
            out[0] = r.x / nv + r.w / nnoise;
        }
    }
}

extern "C" void kernel_launch(void* const* d_in, const int* in_sizes, int n_in,
                              void* d_out, int out_size, void* d_ws, size_t ws_size,
                              hipStream_t stream) {
    const float*  pred_beta    = (const float*)d_in[0];
    const float2* pred_ccoords = (const float2*)d_in[1];
    const float*  pred_energy  = (const float*)d_in[2];
    const float2* pred_pos     = (const float2*)d_in[3];
    const float*  pred_time    = (const float*)d_in[4];
    const float2* pred_id2     = (const float2*)d_in[5];
    const float*  t_energy     = (const float*)d_in[6];
    const float2* t_pos        = (const float2*)d_in[7];
    const float*  t_time       = (const float*)d_in[8];
    const int*    t_idx        = (const int*)d_in[10];
    int n = in_sizes[0];
    int nbh = (n + CHUNK - 1) / CHUNK;   // 500 for n=100000
    int hstr = (nbh + 8) & ~7;           // padded row stride (504)

    // workspace carve (16B-aligned)
    char* base = (char*)d_ws;
    size_t off = 0;
    u64*    pk_part    = (u64*)   (base + off); off += (size_t)KOBJ * B1 * 8;    // 512 KB
    float*  cnt_part   = (float*) (base + off); off += (size_t)KOBJ * B1 * 4;    // 256 KB
    float*  den_part   = (float*) (base + off); off += (size_t)KOBJ * B1 * 4;    // 256 KB
    float*  num_part   = (float*) (base + off); off += (size_t)KOBJ * B1 * 4;    // 256 KB
    float*  noise_part = (float*) (base + off); off += 256 * 4;
    float4* objA       = (float4*)(base + off); off += KOBJ * 16;
    float4* objB       = (float4*)(base + off); off += KOBJ * 16;
    float*  objCf      = (float*) (base + off); off += KOBJ * 4 * 4;             // 4 KB
    unsigned* tick     = (unsigned*)(base + off); off += 16;
    float*  rep_part   = (float*) (base + off); off += (size_t)KOBJ * hstr * 4;  // ~516 KB
    float*  att_part   = (float*) (base + off); off += (size_t)KOBJ * hstr * 4;

    partials<<<B1, 256, 0, stream>>>(pred_beta, pred_energy, pred_pos, pred_time,
                                     pred_id2, t_energy, t_pos, t_time, t_idx,
                                     pk_part, cnt_part, den_part, num_part, noise_part,
                                     tick, n);
    merge<<<KOBJ, 256, 0, stream>>>(pred_ccoords, pk_part, cnt_part, den_part, num_part,
                                    objA, objB);
    heavy<<<nbh, 256, 0, stream>>>(pred_beta, pred_ccoords, t_idx, objA,
                                   rep_part, att_part, n, hstr);
    finalk<<<KOBJ, 256, 0, stream>>>(objA, objB, rep_part, att_part, noise_part,
                                     objCf, tick, (float*)d_out, n, nbh, hstr);
}

// Round 2
// 106.303 us; speedup vs baseline: 1.0097x; 1.0097x over previous
//
#include <hip/hip_runtime.h>
#include <math.h>

#define KOBJ 256
#define B1   256              // partial-accumulator blocks
#define NW   4                // waves per block
#define WSTR 257              // per-wave bucket stride (bank-conflict pad)
#define QMIN 0.5f
#define BETA_CLIP_C (1.0f - 1e-5f)

typedef unsigned long long u64;

// ---------------- Kernel A: per-block LDS accumulation with PER-WAVE buckets
// (removes same-address inter-wave atomic serialization), k-major partial writes.
__global__ __launch_bounds__(256) void partials(
    const float*  __restrict__ pred_beta,
    const float*  __restrict__ pred_energy,
    const float2* __restrict__ pred_pos,
    const float*  __restrict__ pred_time,
    const float2* __restrict__ pred_id2,
    const float*  __restrict__ t_energy,
    const float2* __restrict__ t_pos,
    const float*  __restrict__ t_time,
    const int*    __restrict__ t_idx,
    u64*    __restrict__ pk_part,   // [K][B1]
    float*  __restrict__ cnt_part,  // [K][B1]
    float*  __restrict__ den_part,  // [K][B1]
    float*  __restrict__ num_part,  // [K][B1]
    float*  __restrict__ noise_part,// [B1]
    int n)
{
    __shared__ u64   spk[NW][WSTR];                   // 8.2 KB
    __shared__ float scnt[NW][WSTR], sden[NW][WSTR], snum[NW][WSTR]; // 12.3 KB
    __shared__ float snoise[256];
    int t = threadIdx.x;
    int b = blockIdx.x;
    int w = t >> 6;
    for (int i = t; i < NW * WSTR; i += 256) {
        ((u64*)spk)[i] = 0;
        ((float*)scnt)[i] = 0.f;
        ((float*)sden)[i] = 0.f;
        ((float*)snum)[i] = 0.f;
    }
    __syncthreads();

    float noise = 0.0f;
    for (int i = b * 256 + t; i < n; i += B1 * 256) {
        int tid = t_idx[i];
        float braw = pred_beta[i];
        float beta = fminf(fmaxf(braw, 0.0f), BETA_CLIP_C);
        if (tid >= 0) {
            atomicAdd(&scnt[w][tid], 1.0f);
            u64 key = ((u64)__float_as_uint(beta) << 32) |
                      (u64)(0x7FFFFFFFu - (unsigned)i);   // max beta, tie -> lowest index
            atomicMax(&spk[w][tid], key);
            float te = t_energy[i];
            float ew = (te > 10.0f) ? 1.0f : fmaxf(0.0f, (te - 0.5f) / 9.5f);
            float de = te - pred_energy[i];
            float el = de * de / (te + 1.0f);
            float2 tp = t_pos[i];
            float2 pp = pred_pos[i];
            float dpx = tp.x - pp.x, dpy = tp.y - pp.y;
            float pl = (dpx * dpx + dpy * dpy) * 0.01f;
            float dt = t_time[i] - pred_time[i];
            float tl = dt * dt;
            float2 id0 = pred_id2[3 * i];
            float2 id1 = pred_id2[3 * i + 1];
            float2 id2 = pred_id2[3 * i + 2];
            float cs = id0.x * id0.x + id0.y * id0.y + id1.x * id1.x +
                       id1.y * id1.y + id2.x * id2.x + id2.y * id2.y;
            cs *= (1e-8f / 6.0f);
            float mask = (braw < 0.1f) ? 0.0f : 1.0f;  // PAYLOAD_BETA_CLIP on raw beta
            float wgt = mask * ew * beta;
            atomicAdd(&sden[w][tid], beta);
            atomicAdd(&snum[w][tid], (el + pl + tl + cs) * wgt);
        } else {
            noise += beta;
        }
    }
    __syncthreads();
    // fold 4 wave-buckets -> 1 (stride-1 reads, conflict-free)
    u64 pk = spk[0][t];
    { u64 q = spk[1][t]; if (q > pk) pk = q; }
    { u64 q = spk[2][t]; if (q > pk) pk = q; }
    { u64 q = spk[3][t]; if (q > pk) pk = q; }
    float cnt = scnt[0][t] + scnt[1][t] + scnt[2][t] + scnt[3][t];
    float den = sden[0][t] + sden[1][t] + sden[2][t] + sden[3][t];
    float num = snum[0][t] + snum[1][t] + snum[2][t] + snum[3][t];
    int o = t * B1 + b;
    pk_part[o]  = pk;
    cnt_part[o] = cnt;
    den_part[o] = den;
    num_part[o] = num;
    snoise[t] = noise;
    __syncthreads();
    for (int s = 128; s > 0; s >>= 1) {
        if (t < s) snoise[t] += snoise[t + s];
        __syncthreads();
    }
    if (t == 0) noise_part[b] = snoise[0];
}

// ---------------- Kernel B: one block per object; coalesced row reduce
__global__ __launch_bounds__(256) void merge(
    const float2* __restrict__ pred_ccoords,
    const u64*    __restrict__ pk_part,
    const float*  __restrict__ cnt_part,
    const float*  __restrict__ den_part,
    const float*  __restrict__ num_part,
    float4* __restrict__ objA,   // (xk, yk, qa, cnt)
    float4* __restrict__ objB)   // (pay, lb, valid, 0)
{
    __shared__ u64   spk[256];
    __shared__ float scnt[256], sden[256], snum[256];
    int k = blockIdx.x;
    int b = threadIdx.x;
    int o = k * B1 + b;
    u64 pk = pk_part[o];
    float cnt = cnt_part[o];
    float den = den_part[o];
    float nsum = num_part[o];
    spk[b] = pk; scnt[b] = cnt; sden[b] = den; snum[b] = nsum;
    __syncthreads();
    for (int s = 128; s > 0; s >>= 1) {
        if (b < s) {
            u64 p = spk[b + s]; if (p > spk[b]) spk[b] = p;
            scnt[b] += scnt[b + s];
            sden[b] += sden[b + s];
            snum[b] += snum[b + s];
        }
        __syncthreads();
    }
    if (b == 0) {
        float cs = scnt[0];
        bool valid = cs > 0.f;
        float xk = 0.f, yk = 0.f, qa = 0.f, lb = 0.f, pay = 0.f;
        if (valid) {
            u64 p = spk[0];
            unsigned a = 0x7FFFFFFFu - (unsigned)(p & 0xFFFFFFFFull);
            float ba = __uint_as_float((unsigned)(p >> 32));
            float2 cc = pred_ccoords[a];
            xk = cc.x; yk = cc.y;
            float at = atanhf(ba);
            qa = at * at + QMIN;
            lb = 1.0f - ba;
            pay = snum[0] / fmaxf(sden[0], 1e-6f);
        }
        objA[k] = make_float4(xk, yk, qa, cs);
        objB[k] = make_float4(pay, lb, valid ? 1.f : 0.f, 0.f);
    }
}

// ---------------- Kernel C: N x K repulsion-only hot loop (8 VALU ops/pair);
// attraction + own-pair exclusion handled as an O(N) per-block LDS correction
// (numerics validated in R1: absmax 0.0). CHUNK=256, grid 391 (throughput-bound;
// all blocks co-resident, so smaller grid = less per-block overhead).
__global__ __launch_bounds__(256) void heavy(
    const float*  __restrict__ pred_beta,
    const float2* __restrict__ pred_ccoords,
    const int*    __restrict__ t_idx,
    const float4* __restrict__ objA,
    float* __restrict__ rep_part,   // [K][hstr]
    float* __restrict__ att_part,   // [K][hstr]
    int n, int hstr)
{
    __shared__ float4 pts[256];
    __shared__ float corrR[KOBJ], corrA[KOBJ];
    int t = threadIdx.x;
    corrR[t] = 0.f;
    corrA[t] = 0.f;
    int p = blockIdx.x * 256 + t;
    float4 pt;
    if (p < n) {
        float beta = fminf(fmaxf(pred_beta[p], 0.0f), BETA_CLIP_C);
        float at = atanhf(beta);
        float2 cc = pred_ccoords[p];
        pt = make_float4(cc.x, cc.y, at * at + QMIN, __int_as_float(t_idx[p]));
    } else {
        pt = make_float4(0.f, 0.f, 0.f, __int_as_float(-2));  // q=0 => inert
    }
    pts[t] = pt;
    float4 oa = objA[t];
    float xk = oa.x, yk = oa.y;
    __syncthreads();   // covers corr zeroing + pts store

    // own-pair correction: thread t handles its own point (register pt).
    // att_k  = sum_{i in k} d2(i, x_k) * q_i   (this IS the attraction numerator)
    // corrR removes the own-pair h*q the unconditional loop below adds.
    int tid = __float_as_int(pt.w);
    if (tid >= 0) {
        float4 ok = objA[tid];                         // 4 KB table, L1-hot
        float dx = pt.x - ok.x, dy = pt.y - ok.y;
        float d2 = fmaf(dy, dy, fmaf(dx, dx, 1e-6f));  // eps folded (accepted numerics)
        float r = __builtin_amdgcn_sqrtf(d2);
        float h = fmaxf(0.0f, 1.0f - r);
        atomicAdd(&corrA[tid], d2 * pt.z);
        atomicAdd(&corrR[tid], h * pt.z);
    }

    float rep = 0.f;
    #pragma unroll 8
    for (int j = 0; j < 256; ++j) {
        float4 s = pts[j];                    // wave-uniform address -> bank broadcast
        float dx = s.x - xk, dy = s.y - yk;
        float d2 = fmaf(dy, dy, fmaf(dx, dx, 1e-6f));
        float r = __builtin_amdgcn_sqrtf(d2);
        float h = fmaxf(0.0f, 1.0f - r);
        rep = fmaf(h, s.z, rep);              // unconditional; own pairs removed via corrR
    }
    __syncthreads();   // all correction atomics visible
    int o = t * hstr + blockIdx.x;
    rep_part[o] = rep - corrR[t];
    att_part[o] = corrA[t];
}

// ---------------- Kernel D1: per-object reduce of heavy partials (coalesced rows)
__global__ __launch_bounds__(256) void final1(
    const float4* __restrict__ objA,
    const float4* __restrict__ objB,
    const float*  __restrict__ rep_part,
    const float*  __restrict__ att_part,
    float4* __restrict__ objC,   // (s0, valid, cnt, 0)
    int n, int nbh, int hstr)
{
    __shared__ float srep[256], satt[256];
    int k = blockIdx.x;
    int b = threadIdx.x;
    float rep = 0.f, att = 0.f;
    int o = k * hstr + b;
    if (b < nbh)        { rep += rep_part[o];        att += att_part[o]; }
    if (b + 256 < nbh)  { rep += rep_part[o + 256];  att += att_part[o + 256]; }
    srep[b] = rep; satt[b] = att;
    __syncthreads();
    for (int s = 128; s > 0; s >>= 1) {
        if (b < s) { srep[b] += srep[b + s]; satt[b] += satt[b + s]; }
        __syncthreads();
    }
    if (b == 0) {
        float4 a  = objA[k];
        float4 b4 = objB[k];
        float cnt = a.w, qa = a.z, valid = b4.z;
        float vatt = valid * satt[0] * qa / fmaxf(cnt, 1.0f);
        float vrep = valid * srep[0] * qa / fmaxf((float)n - cnt, 1.0f);
        objC[k] = make_float4(vatt + vrep + b4.y + b4.x, valid, cnt, 0.f);
    }
}

// ---------------- Kernel D2: scalar finish
__global__ __launch_bounds__(256) void final2(
    const float4* __restrict__ objC,
    const float*  __restrict__ noise_part,
    float* __restrict__ out, int n)
{
    __shared__ float4 sred[256];
    int t = threadIdx.x;
    float4 c = objC[t];
    c.w = noise_part[t];
    sred[t] = c;
    __syncthreads();
    for (int s = 128; s > 0; s >>= 1) {
        if (t < s) {
            float4 x = sred[t], y = sred[t + s];
            sred[t] = make_float4(x.x + y.x, x.y + y.y, x.z + y.z, x.w + y.w);
        }
        __syncthreads();
    }
    if (t == 0) {
        float4 r = sred[0];
        float nv = fmaxf(r.y, 1.0f);                    // n_valid
        float nnoise = fmaxf((float)n - r.z, 1.0f);     // noise count
        out[0] = r.x / nv + r.w / nnoise;
    }
}

extern "C" void kernel_launch(void* const* d_in, const int* in_sizes, int n_in,
                              void* d_out, int out_size, void* d_ws, size_t ws_size,
                              hipStream_t stream) {
    const float*  pred_beta    = (const float*)d_in[0];
    const float2* pred_ccoords = (const float2*)d_in[1];
    const float*  pred_energy  = (const float*)d_in[2];
    const float2* pred_pos     = (const float2*)d_in[3];
    const float*  pred_time    = (const float*)d_in[4];
    const float2* pred_id2     = (const float2*)d_in[5];
    const float*  t_energy     = (const float*)d_in[6];
    const float2* t_pos        = (const float2*)d_in[7];
    const float*  t_time       = (const float*)d_in[8];
    const int*    t_idx        = (const int*)d_in[10];
    int n = in_sizes[0];
    int nbh = (n + 255) / 256;          // 391 for n=100000
    int hstr = (nbh + 8) & ~7;          // padded row stride (392)

    // workspace carve (16B-aligned)
    char* base = (char*)d_ws;
    size_t off = 0;
    u64*    pk_part    = (u64*)   (base + off); off += (size_t)KOBJ * B1 * 8;    // 512 KB
    float*  cnt_part   = (float*) (base + off); off += (size_t)KOBJ * B1 * 4;    // 256 KB
    float*  den_part   = (float*) (base + off); off += (size_t)KOBJ * B1 * 4;    // 256 KB
    float*  num_part   = (float*) (base + off); off += (size_t)KOBJ * B1 * 4;    // 256 KB
    float*  noise_part = (float*) (base + off); off += 256 * 4;
    float4* objA       = (float4*)(base + off); off += KOBJ * 16;
    float4* objB       = (float4*)(base + off); off += KOBJ * 16;
    float4* objC       = (float4*)(base + off); off += KOBJ * 16;
    float*  rep_part   = (float*) (base + off); off += (size_t)KOBJ * hstr * 4;  // ~400 KB
    float*  att_part   = (float*) (base + off); off += (size_t)KOBJ * hstr * 4;

    partials<<<B1, 256, 0, stream>>>(pred_beta, pred_energy, pred_pos, pred_time,
                                     pred_id2, t_energy, t_pos, t_time, t_idx,
                                     pk_part, cnt_part, den_part, num_part, noise_part, n);
    merge<<<KOBJ, 256, 0, stream>>>(pred_ccoords, pk_part, cnt_part, den_part, num_part,
                                    objA, objB);
    heavy<<<nbh, 256, 0, stream>>>(pred_beta, pred_ccoords, t_idx, objA,
                                   rep_part, att_part, n, hstr);
    final1<<<KOBJ, 256, 0, stream>>>(objA, objB, rep_part, att_part, objC, n, nbh, hstr);
    final2<<<1, 256, 0, stream>>>(objC, noise_part, (float*)d_out, n);
}